// Round 1
// baseline (469.483 us; speedup 1.0000x reference)
//
#include <hip/hip_runtime.h>

#define HW 262144
#define WID 512
#define PLANES 48
#define NBATCH 16
#define NCH 3
#define PAD 11
#define FW 23

// ---------------- median per plane (2-pass histogram refine) ----------------
__global__ __launch_bounds__(256) void median_kernel(const float* __restrict__ x,
                                                     float* __restrict__ med_out) {
  __shared__ int h[8192];
  __shared__ int csum[256];
  __shared__ int s_bin, s_rank;
  const int p = blockIdx.x;
  const int tid = threadIdx.x;
  const float4* xv = (const float4*)(x + (size_t)p * HW);

  for (int i = tid; i < 8192; i += 256) h[i] = 0;
  __syncthreads();
  for (int i = tid; i < HW / 4; i += 256) {
    float4 v = xv[i];
    int b;
    b = (int)((v.x + 8.0f) * 512.0f); b = min(max(b, 0), 8191); atomicAdd(&h[b], 1);
    b = (int)((v.y + 8.0f) * 512.0f); b = min(max(b, 0), 8191); atomicAdd(&h[b], 1);
    b = (int)((v.z + 8.0f) * 512.0f); b = min(max(b, 0), 8191); atomicAdd(&h[b], 1);
    b = (int)((v.w + 8.0f) * 512.0f); b = min(max(b, 0), 8191); atomicAdd(&h[b], 1);
  }
  __syncthreads();
  {
    int s = 0;
#pragma unroll
    for (int j = 0; j < 32; ++j) s += h[tid * 32 + j];
    csum[tid] = s;
  }
  __syncthreads();
  if (tid == 0) {
    const int rank = 131072;  // 1-based rank of sorted index (HW-1)/2
    int cum = 0, ch = 0;
    for (; ch < 255; ++ch) { if (cum + csum[ch] >= rank) break; cum += csum[ch]; }
    int b = ch * 32;
    for (int j = 0; j < 32; ++j) { if (cum + h[b] >= rank) break; cum += h[b]; ++b; }
    if (b > 8191) b = 8191;
    s_bin = b; s_rank = rank - cum;
  }
  __syncthreads();
  const int bin1 = s_bin;
  const int rank2 = s_rank;
  const float lo = -8.0f + (float)bin1 * 0.001953125f;  // exact in fp32
  __syncthreads();
  for (int i = tid; i < 8192; i += 256) h[i] = 0;
  __syncthreads();
#define PASS2(c) { int b1 = (int)(((c) + 8.0f) * 512.0f); b1 = min(max(b1, 0), 8191); \
  if (b1 == bin1) { int b2 = (int)(((c) - lo) * 4194304.0f); b2 = min(max(b2, 0), 8191); atomicAdd(&h[b2], 1); } }
  for (int i = tid; i < HW / 4; i += 256) {
    float4 v = xv[i];
    PASS2(v.x); PASS2(v.y); PASS2(v.z); PASS2(v.w);
  }
#undef PASS2
  __syncthreads();
  {
    int s = 0;
#pragma unroll
    for (int j = 0; j < 32; ++j) s += h[tid * 32 + j];
    csum[tid] = s;
  }
  __syncthreads();
  if (tid == 0) {
    int cum = 0, ch = 0;
    for (; ch < 255; ++ch) { if (cum + csum[ch] >= rank2) break; cum += csum[ch]; }
    int b = ch * 32;
    for (int j = 0; j < 32; ++j) { if (cum + h[b] >= rank2) break; cum += h[b]; ++b; }
    if (b > 8191) b = 8191;
    const float w2 = 0.001953125f / 8192.0f;  // 2^-22
    med_out[p] = lo + ((float)b + 0.5f) * w2 + 0.2f;
  }
}

// ---------------- separable 23x23 conv + res, tiled ----------------
// tile 64x64 out, halo 11 each side -> 86x86 in
__global__ __launch_bounds__(256) void conv_kernel(const float* __restrict__ x,
                                                   const float* __restrict__ mask,
                                                   const float* __restrict__ kern,
                                                   const float* __restrict__ med,
                                                   float* __restrict__ res) {
  __shared__ float xs[86][88];  // +2 pad on stride
  __shared__ float hs[86][64];
  __shared__ float k1[FW];
  const int z = blockIdx.z;          // plane 0..47
  const int n = z / NCH;
  const int tx = blockIdx.x, ty = blockIdx.y;
  const int tid = threadIdx.x;

  if (tid < FW) {
    float a = kern[tid * FW + PAD];
    float c = kern[PAD * FW + PAD];
    k1[tid] = a / sqrtf(c);
  }
  const float m_med = med[z];
  const int gx0 = ty * 64 - PAD;
  const int gy0 = tx * 64 - PAD;
  const float* xb = x + (size_t)z * HW;
  const float* mb = mask + (size_t)n * HW;
  for (int i = tid; i < 86 * 86; i += 256) {
    int r = i / 86, c = i - r * 86;
    int gr = min(max(gx0 + r, 0), WID - 1);
    int gc = min(max(gy0 + c, 0), WID - 1);
    int g = gr * WID + gc;
    float xvv = xb[g];
    float mv = mb[g];
    xs[r][c] = mv * xvv + (1.0f - mv) * m_med;
  }
  __syncthreads();
  for (int i = tid; i < 86 * 64; i += 256) {
    int r = i >> 6, c = i & 63;
    float s = 0.0f;
#pragma unroll
    for (int t = 0; t < FW; ++t) s += k1[t] * xs[r][c + t];
    hs[r][c] = s;
  }
  __syncthreads();
  float* rb = res + (size_t)z * HW;
  for (int i = tid; i < 64 * 64; i += 256) {
    int r = i >> 6, c = i & 63;
    float g = 0.0f;
#pragma unroll
    for (int t = 0; t < FW; ++t) g += k1[t] * hs[r + t][c];
    float xpv = xs[r + PAD][c + PAD];
    float rv = 4.0f * (xpv - g);
    rb[(size_t)(ty * 64 + r) * WID + (tx * 64 + c)] = rv;
  }
}

// ---------------- per-plane histogram of trunc(res*256) ----------------
__global__ __launch_bounds__(256) void hist_kernel(const float* __restrict__ res,
                                                   int* __restrict__ ghist) {
  __shared__ int h[16384];
  const int p = blockIdx.x;   // plane
  const int s = blockIdx.y;   // slice 0..7
  const int tid = threadIdx.x;
  for (int i = tid; i < 16384; i += 256) h[i] = 0;
  __syncthreads();
  const float4* rv = (const float4*)(res + (size_t)p * HW + (size_t)s * 32768);
#define HADD(c) { int b = (int)((c) * 256.0f) + 8192; b = min(max(b, 0), 16383); atomicAdd(&h[b], 1); }
  for (int i = tid; i < 8192; i += 256) {
    float4 v = rv[i];
    HADD(v.x); HADD(v.y); HADD(v.z); HADD(v.w);
  }
#undef HADD
  __syncthreads();
  int* gh = ghist + p * 16384;
  for (int i = tid; i < 16384; i += 256) {
    int c = h[i];
    if (c) atomicAdd(&gh[i], c);
  }
}

// ---------------- percentile scan (np.percentile linear interp) ----------------
__global__ __launch_bounds__(256) void pct_kernel(const int* __restrict__ ghist,
                                                  float* __restrict__ lo_out,
                                                  float* __restrict__ inv_out) {
  __shared__ int csum[256];
  const int p = blockIdx.x;
  const int tid = threadIdx.x;
  const int* gh = ghist + p * 16384;
  int s = 0;
  for (int j = 0; j < 64; ++j) s += gh[tid * 64 + j];
  csum[tid] = s;
  __syncthreads();
  if (tid == 0) {
    auto find_rank = [&](int rank) -> float {
      int cum = 0, ch = 0;
      for (; ch < 255; ++ch) { if (cum + csum[ch] >= rank) break; cum += csum[ch]; }
      int b = ch * 64;
      for (int j = 0; j < 64; ++j) { if (cum + gh[b] >= rank) break; cum += gh[b]; ++b; }
      if (b > 16383) b = 16383;
      return (float)(b - 8192) * 0.00390625f;
    };
    double pl = 3.0 / 100.0 * (double)(HW - 1);
    int kl = (int)floor(pl);
    double fl = pl - floor(pl);
    float v0 = find_rank(kl + 1);
    float v1 = find_rank(kl + 2);
    double lov = (double)v0 + fl * ((double)v1 - (double)v0);
    double ph = 97.0 / 100.0 * (double)(HW - 1);
    int kh = (int)floor(ph);
    double fh = ph - floor(ph);
    float w0 = find_rank(kh + 1);
    float w1 = find_rank(kh + 2);
    double hiv = (double)w0 + fh * ((double)w1 - (double)w0);
    lo_out[p] = (float)lov;
    inv_out[p] = (float)(1.0 / (hiv - lov));
  }
}

// ---------------- final normalize in place (res lives in d_out) ----------------
__global__ __launch_bounds__(256) void final_kernel(float* __restrict__ res,
                                                    const float* __restrict__ mask,
                                                    const float* __restrict__ lo,
                                                    const float* __restrict__ inv) {
  const int i = blockIdx.x * 256 + threadIdx.x;  // float4 id, total 3145728
  const int e = i << 2;
  const int z = e >> 18;
  const int n = z / NCH;
  const int hw = e & (HW - 1);
  float4 r = ((const float4*)res)[i];
  float4 m = *(const float4*)(mask + (size_t)n * HW + hw);
  const float l = lo[z];
  const float iv = inv[z];
  float4 o;
  o.x = (r.x - l) * iv * m.x;
  o.y = (r.y - l) * iv * m.y;
  o.z = (r.z - l) * iv * m.z;
  o.w = (r.w - l) * iv * m.w;
  ((float4*)res)[i] = o;
}

extern "C" void kernel_launch(void* const* d_in, const int* in_sizes, int n_in,
                              void* d_out, int out_size, void* d_ws, size_t ws_size,
                              hipStream_t stream) {
  (void)in_sizes; (void)n_in; (void)out_size; (void)ws_size;
  const float* x = (const float*)d_in[0];
  const float* mask = (const float*)d_in[1];
  const float* kern = (const float*)d_in[2];
  float* out = (float*)d_out;          // doubles as res scratch
  float* wsf = (float*)d_ws;
  int* hist = (int*)wsf;               // 48 * 16384 ints
  float* med = wsf + PLANES * 16384;
  float* lo = med + PLANES;
  float* inv = lo + PLANES;

  hipMemsetAsync(hist, 0, (size_t)PLANES * 16384 * sizeof(int), stream);
  median_kernel<<<PLANES, 256, 0, stream>>>(x, med);
  conv_kernel<<<dim3(8, 8, PLANES), 256, 0, stream>>>(x, mask, kern, med, out);
  hist_kernel<<<dim3(PLANES, 8), 256, 0, stream>>>(out, hist);
  pct_kernel<<<PLANES, 256, 0, stream>>>(hist, lo, inv);
  final_kernel<<<(HW * PLANES / 4 + 255) / 256, 256, 0, stream>>>(out, mask, lo, inv);
}

// Round 2
// 287.702 us; speedup vs baseline: 1.6318x; 1.6318x over previous
//
#include <hip/hip_runtime.h>

#define HW 262144
#define WID 512
#define PLANES 48
#define NBATCH 16
#define NCH 3
#define PAD 11
#define FW 23

// ============ median stage: distributed 2-pass histogram ============
// pass 1: 1024 coarse bins over [-8,8), width 1/64
__global__ __launch_bounds__(256) void hist1_kernel(const float* __restrict__ x,
                                                    int* __restrict__ ghist1) {
  __shared__ int h[1024];
  const int p = blockIdx.x, s = blockIdx.y, tid = threadIdx.x;
  for (int i = tid; i < 1024; i += 256) h[i] = 0;
  __syncthreads();
  const float4* xv = (const float4*)(x + (size_t)p * HW + (size_t)s * (HW / 64));
#define H1(c) { int b = (int)(((c) + 8.0f) * 64.0f); b = min(max(b, 0), 1023); atomicAdd(&h[b], 1); }
  for (int i = tid; i < HW / 64 / 4; i += 256) {
    float4 v = xv[i];
    H1(v.x); H1(v.y); H1(v.z); H1(v.w);
  }
#undef H1
  __syncthreads();
  int* gh = ghist1 + p * 1024;
  for (int i = tid; i < 1024; i += 256) {
    int c = h[i];
    if (c) atomicAdd(&gh[i], c);
  }
}

__global__ __launch_bounds__(256) void scan1_kernel(const int* __restrict__ ghist1,
                                                    int* __restrict__ bin1,
                                                    int* __restrict__ rank2) {
  __shared__ int csum[256];
  const int p = blockIdx.x, tid = threadIdx.x;
  const int* gh = ghist1 + p * 1024;
  int s = 0;
#pragma unroll
  for (int j = 0; j < 4; ++j) s += gh[tid * 4 + j];
  csum[tid] = s;
  __syncthreads();
  if (tid == 0) {
    const int rank = 131072;  // 1-based rank of sorted idx (HW-1)/2
    int cum = 0, ch = 0;
    for (; ch < 255; ++ch) { if (cum + csum[ch] >= rank) break; cum += csum[ch]; }
    int b = ch * 4;
    for (int j = 0; j < 4; ++j) { if (cum + gh[b] >= rank) break; cum += gh[b]; ++b; }
    if (b > 1023) b = 1023;
    bin1[p] = b;
    rank2[p] = rank - cum;
  }
}

// pass 2: refine selected coarse bin into 8192 sub-bins (width 2^-19)
__global__ __launch_bounds__(256) void hist2_kernel(const float* __restrict__ x,
                                                    const int* __restrict__ bin1,
                                                    int* __restrict__ ghist2) {
  __shared__ int h[8192];
  __shared__ int sb;
  const int p = blockIdx.x, s = blockIdx.y, tid = threadIdx.x;
  if (tid == 0) sb = bin1[p];
  for (int i = tid; i < 8192; i += 256) h[i] = 0;
  __syncthreads();
  const int b1 = sb;
  const float blo = -8.0f + (float)b1 * 0.015625f;  // exact fp32
  const float4* xv = (const float4*)(x + (size_t)p * HW + (size_t)s * (HW / 64));
#define H2(c) { int b = (int)(((c) + 8.0f) * 64.0f); b = min(max(b, 0), 1023); \
  if (b == b1) { int b2 = (int)(((c) - blo) * 524288.0f); b2 = min(max(b2, 0), 8191); atomicAdd(&h[b2], 1); } }
  for (int i = tid; i < HW / 64 / 4; i += 256) {
    float4 v = xv[i];
    H2(v.x); H2(v.y); H2(v.z); H2(v.w);
  }
#undef H2
  __syncthreads();
  int* gh = ghist2 + p * 8192;
  for (int i = tid; i < 8192; i += 256) {
    int c = h[i];
    if (c) atomicAdd(&gh[i], c);
  }
}

__global__ __launch_bounds__(256) void scan2_kernel(const int* __restrict__ ghist2,
                                                    const int* __restrict__ bin1,
                                                    const int* __restrict__ rank2,
                                                    float* __restrict__ med) {
  __shared__ int csum[256];
  const int p = blockIdx.x, tid = threadIdx.x;
  const int* gh = ghist2 + p * 8192;
  int s = 0;
#pragma unroll
  for (int j = 0; j < 32; ++j) s += gh[tid * 32 + j];
  csum[tid] = s;
  __syncthreads();
  if (tid == 0) {
    const int rank = rank2[p];
    int cum = 0, ch = 0;
    for (; ch < 255; ++ch) { if (cum + csum[ch] >= rank) break; cum += csum[ch]; }
    int b = ch * 32;
    for (int j = 0; j < 32; ++j) { if (cum + gh[b] >= rank) break; cum += gh[b]; ++b; }
    if (b > 8191) b = 8191;
    const float blo = -8.0f + (float)bin1[p] * 0.015625f;
    med[p] = blo + ((float)b + 0.5f) * 1.9073486328125e-6f + 0.2f;  // 2^-19
  }
}

// ---------------- separable 23x23 conv + res, tiled ----------------
// tile 64x64 out, halo 11 each side -> 86x86 in
__global__ __launch_bounds__(256) void conv_kernel(const float* __restrict__ x,
                                                   const float* __restrict__ mask,
                                                   const float* __restrict__ kern,
                                                   const float* __restrict__ med,
                                                   float* __restrict__ res) {
  __shared__ float xs[86][88];  // +2 pad on stride
  __shared__ float hs[86][64];
  __shared__ float k1[FW];
  const int z = blockIdx.z;          // plane 0..47
  const int n = z / NCH;
  const int tx = blockIdx.x, ty = blockIdx.y;
  const int tid = threadIdx.x;

  if (tid < FW) {
    float a = kern[tid * FW + PAD];
    float c = kern[PAD * FW + PAD];
    k1[tid] = a / sqrtf(c);
  }
  const float m_med = med[z];
  const int gx0 = ty * 64 - PAD;
  const int gy0 = tx * 64 - PAD;
  const float* xb = x + (size_t)z * HW;
  const float* mb = mask + (size_t)n * HW;
  for (int i = tid; i < 86 * 86; i += 256) {
    int r = i / 86, c = i - r * 86;
    int gr = min(max(gx0 + r, 0), WID - 1);
    int gc = min(max(gy0 + c, 0), WID - 1);
    int g = gr * WID + gc;
    float xvv = xb[g];
    float mv = mb[g];
    xs[r][c] = mv * xvv + (1.0f - mv) * m_med;
  }
  __syncthreads();
  for (int i = tid; i < 86 * 64; i += 256) {
    int r = i >> 6, c = i & 63;
    float s = 0.0f;
#pragma unroll
    for (int t = 0; t < FW; ++t) s += k1[t] * xs[r][c + t];
    hs[r][c] = s;
  }
  __syncthreads();
  float* rb = res + (size_t)z * HW;
  for (int i = tid; i < 64 * 64; i += 256) {
    int r = i >> 6, c = i & 63;
    float g = 0.0f;
#pragma unroll
    for (int t = 0; t < FW; ++t) g += k1[t] * hs[r + t][c];
    float xpv = xs[r + PAD][c + PAD];
    float rv = 4.0f * (xpv - g);
    rb[(size_t)(ty * 64 + r) * WID + (tx * 64 + c)] = rv;
  }
}

// ---------------- per-plane histogram of trunc(res*256) ----------------
__global__ __launch_bounds__(256) void hist_kernel(const float* __restrict__ res,
                                                   int* __restrict__ ghist) {
  __shared__ int h[16384];
  const int p = blockIdx.x;   // plane
  const int s = blockIdx.y;   // slice 0..7
  const int tid = threadIdx.x;
  for (int i = tid; i < 16384; i += 256) h[i] = 0;
  __syncthreads();
  const float4* rv = (const float4*)(res + (size_t)p * HW + (size_t)s * 32768);
#define HADD(c) { int b = (int)((c) * 256.0f) + 8192; b = min(max(b, 0), 16383); atomicAdd(&h[b], 1); }
  for (int i = tid; i < 8192; i += 256) {
    float4 v = rv[i];
    HADD(v.x); HADD(v.y); HADD(v.z); HADD(v.w);
  }
#undef HADD
  __syncthreads();
  int* gh = ghist + p * 16384;
  for (int i = tid; i < 16384; i += 256) {
    int c = h[i];
    if (c) atomicAdd(&gh[i], c);
  }
}

// ---------------- percentile scan (np.percentile linear interp) ----------------
__global__ __launch_bounds__(256) void pct_kernel(const int* __restrict__ ghist,
                                                  float* __restrict__ lo_out,
                                                  float* __restrict__ inv_out) {
  __shared__ int csum[256];
  const int p = blockIdx.x;
  const int tid = threadIdx.x;
  const int* gh = ghist + p * 16384;
  int s = 0;
  for (int j = 0; j < 64; ++j) s += gh[tid * 64 + j];
  csum[tid] = s;
  __syncthreads();
  if (tid == 0) {
    auto find_rank = [&](int rank) -> float {
      int cum = 0, ch = 0;
      for (; ch < 255; ++ch) { if (cum + csum[ch] >= rank) break; cum += csum[ch]; }
      int b = ch * 64;
      for (int j = 0; j < 64; ++j) { if (cum + gh[b] >= rank) break; cum += gh[b]; ++b; }
      if (b > 16383) b = 16383;
      return (float)(b - 8192) * 0.00390625f;
    };
    double pl = 3.0 / 100.0 * (double)(HW - 1);
    int kl = (int)floor(pl);
    double fl = pl - floor(pl);
    float v0 = find_rank(kl + 1);
    float v1 = find_rank(kl + 2);
    double lov = (double)v0 + fl * ((double)v1 - (double)v0);
    double ph = 97.0 / 100.0 * (double)(HW - 1);
    int kh = (int)floor(ph);
    double fh = ph - floor(ph);
    float w0 = find_rank(kh + 1);
    float w1 = find_rank(kh + 2);
    double hiv = (double)w0 + fh * ((double)w1 - (double)w0);
    lo_out[p] = (float)lov;
    inv_out[p] = (float)(1.0 / (hiv - lov));
  }
}

// ---------------- final normalize in place (res lives in d_out) ----------------
__global__ __launch_bounds__(256) void final_kernel(float* __restrict__ res,
                                                    const float* __restrict__ mask,
                                                    const float* __restrict__ lo,
                                                    const float* __restrict__ inv) {
  const int i = blockIdx.x * 256 + threadIdx.x;  // float4 id, total 3145728
  const int e = i << 2;
  const int z = e >> 18;
  const int n = z / NCH;
  const int hw = e & (HW - 1);
  float4 r = ((const float4*)res)[i];
  float4 m = *(const float4*)(mask + (size_t)n * HW + hw);
  const float l = lo[z];
  const float iv = inv[z];
  float4 o;
  o.x = (r.x - l) * iv * m.x;
  o.y = (r.y - l) * iv * m.y;
  o.z = (r.z - l) * iv * m.z;
  o.w = (r.w - l) * iv * m.w;
  ((float4*)res)[i] = o;
}

extern "C" void kernel_launch(void* const* d_in, const int* in_sizes, int n_in,
                              void* d_out, int out_size, void* d_ws, size_t ws_size,
                              hipStream_t stream) {
  (void)in_sizes; (void)n_in; (void)out_size; (void)ws_size;
  const float* x = (const float*)d_in[0];
  const float* mask = (const float*)d_in[1];
  const float* kern = (const float*)d_in[2];
  float* out = (float*)d_out;          // doubles as res scratch

  int* hist = (int*)d_ws;                        // 48*16384
  int* ghist1 = hist + PLANES * 16384;           // 48*1024
  int* ghist2 = ghist1 + PLANES * 1024;          // 48*8192
  int* bin1 = ghist2 + PLANES * 8192;            // 48
  int* rank2 = bin1 + PLANES;                    // 48
  float* med = (float*)(rank2 + PLANES);         // 48
  float* lo = med + PLANES;
  float* inv = lo + PLANES;

  // zero all histograms in one memset (hist..ghist2 contiguous)
  hipMemsetAsync(hist, 0, (size_t)PLANES * (16384 + 1024 + 8192) * sizeof(int), stream);

  hist1_kernel<<<dim3(PLANES, 64), 256, 0, stream>>>(x, ghist1);
  scan1_kernel<<<PLANES, 256, 0, stream>>>(ghist1, bin1, rank2);
  hist2_kernel<<<dim3(PLANES, 64), 256, 0, stream>>>(x, bin1, ghist2);
  scan2_kernel<<<PLANES, 256, 0, stream>>>(ghist2, bin1, rank2, med);

  conv_kernel<<<dim3(8, 8, PLANES), 256, 0, stream>>>(x, mask, kern, med, out);
  hist_kernel<<<dim3(PLANES, 8), 256, 0, stream>>>(out, hist);
  pct_kernel<<<PLANES, 256, 0, stream>>>(hist, lo, inv);
  final_kernel<<<(HW * PLANES / 4 + 255) / 256, 256, 0, stream>>>(out, mask, lo, inv);
}

// Round 3
// 263.669 us; speedup vs baseline: 1.7806x; 1.0911x over previous
//
#include <hip/hip_runtime.h>

#define HW 262144
#define WID 512
#define PLANES 48
#define NCH 3
#define PAD 11
#define FW 23
#define XS 88   // xs row stride (floats)
#define HS 68   // hs row stride (floats)

// ---------- prep: k1[t] = k2[t][11] / sqrt(k2[11][11]) ----------
__global__ __launch_bounds__(64) void kprep_kernel(const float* __restrict__ kern,
                                                   float* __restrict__ k1g) {
  int t = threadIdx.x;
  if (t < FW) k1g[t] = kern[t * FW + PAD] / sqrtf(kern[PAD * FW + PAD]);
}

// ---------- median: single-pass 8192-bin histogram over [-8,8) ----------
__global__ __launch_bounds__(256) void hist1_kernel(const float* __restrict__ x,
                                                    int* __restrict__ ghist1) {
  __shared__ int h[8192];
  const int p = blockIdx.x, s = blockIdx.y, tid = threadIdx.x;
  for (int i = tid; i < 8192; i += 256) h[i] = 0;
  __syncthreads();
  const float4* xv = (const float4*)(x + (size_t)p * HW + (size_t)s * (HW / 16));
#define H1(c) { int b = (int)(((c) + 8.0f) * 512.0f); b = min(max(b, 0), 8191); atomicAdd(&h[b], 1); }
  for (int i = tid; i < HW / 16 / 4; i += 256) {
    float4 v = xv[i];
    H1(v.x); H1(v.y); H1(v.z); H1(v.w);
  }
#undef H1
  __syncthreads();
  int* gh = ghist1 + p * 8192;
  const int st = (s * 512) & 8191;  // stagger flush start per block
  for (int k = tid; k < 8192; k += 256) {
    int i = (k + st) & 8191;
    int c = h[i];
    if (c) atomicAdd(&gh[i], c);
  }
}

__global__ __launch_bounds__(256) void scan_med_kernel(const int* __restrict__ ghist1,
                                                       float* __restrict__ med) {
  __shared__ int csum[256];
  const int p = blockIdx.x, tid = threadIdx.x;
  const int* gh = ghist1 + p * 8192;
  int s = 0;
#pragma unroll
  for (int j = 0; j < 32; ++j) s += gh[tid * 32 + j];
  csum[tid] = s;
  __syncthreads();
  if (tid == 0) {
    const int rank = 131072;  // 1-based rank of sorted idx (HW-1)/2
    int cum = 0, ch = 0;
    for (; ch < 255; ++ch) { if (cum + csum[ch] >= rank) break; cum += csum[ch]; }
    int b = ch * 32;
    for (int j = 0; j < 32; ++j) { if (cum + gh[b] >= rank) break; cum += gh[b]; ++b; }
    if (b > 8191) b = 8191;
    med[p] = -8.0f + ((float)b + 0.5f) * 0.001953125f + 0.2f;  // 2^-9 bins
  }
}

// ---------- separable 23x23 conv, register-tiled 4x4 per thread ----------
__global__ __launch_bounds__(256) void conv_kernel(const float* __restrict__ x,
                                                   const float* __restrict__ mask,
                                                   const float* __restrict__ k1g,
                                                   const float* __restrict__ med,
                                                   float* __restrict__ res) {
  __shared__ float xs[86 * XS];  // 30272 B
  __shared__ float hs[86 * HS];  // 23392 B
  const int z = blockIdx.z;      // plane
  const int n = z / NCH;
  const int tbx = blockIdx.x, tby = blockIdx.y;
  const int tid = threadIdx.x;

  float k1[FW];
#pragma unroll
  for (int t = 0; t < FW; ++t) k1[t] = k1g[t];  // uniform -> scalar-cached

  const float m_med = med[z];
  const int gr0 = tby * 64 - PAD;
  const int gc0 = tbx * 64 - PAD;
  const float* xb = x + (size_t)z * HW;
  const float* mb = mask + (size_t)n * HW;
  for (int i = tid; i < 86 * 86; i += 256) {
    int r = i / 86, c = i - r * 86;
    int gr = min(max(gr0 + r, 0), WID - 1);
    int gc = min(max(gc0 + c, 0), WID - 1);
    int g = gr * WID + gc;
    float xv = xb[g], mv = mb[g];
    xs[r * XS + c] = fmaf(mv, xv - m_med, m_med);  // m*x + (1-m)*med
  }
  __syncthreads();

  // horizontal: hs[r][c] = sum_t k1[t]*xs[r][c+t], r<86, c<64; 4 outputs/group
  for (int g = tid; g < 86 * 16; g += 256) {
    int r = g >> 4, c0 = (g & 15) << 2;
    const float* row = &xs[r * XS + c0];
    float w[28];
#pragma unroll
    for (int q = 0; q < 7; ++q) *(float4*)&w[q * 4] = *(const float4*)(row + q * 4);
    float a0 = 0.f, a1 = 0.f, a2 = 0.f, a3 = 0.f;
#pragma unroll
    for (int t = 0; t < FW; ++t) {
      float k = k1[t];
      a0 = fmaf(k, w[t], a0);
      a1 = fmaf(k, w[t + 1], a1);
      a2 = fmaf(k, w[t + 2], a2);
      a3 = fmaf(k, w[t + 3], a3);
    }
    float4 o; o.x = a0; o.y = a1; o.z = a2; o.w = a3;
    *(float4*)&hs[r * HS + c0] = o;
  }
  __syncthreads();

  // vertical: 4x4 micro-tile per thread; out(r,c) = sum_t k1[t]*hs[r+t][c]
  const int ct = (tid & 15) << 2;
  const int rt = (tid >> 4) << 2;
  float4 acc[4];
#pragma unroll
  for (int j = 0; j < 4; ++j) acc[j] = make_float4(0.f, 0.f, 0.f, 0.f);
#pragma unroll
  for (int tp = 0; tp < 26; ++tp) {
    float4 v = *(const float4*)&hs[(rt + tp) * HS + ct];
    const int jlo = (tp - 22 > 0) ? (tp - 22) : 0;
    const int jhi = (tp < 3) ? tp : 3;
#pragma unroll
    for (int j = jlo; j <= jhi; ++j) {
      float k = k1[tp - j];
      acc[j].x = fmaf(k, v.x, acc[j].x);
      acc[j].y = fmaf(k, v.y, acc[j].y);
      acc[j].z = fmaf(k, v.z, acc[j].z);
      acc[j].w = fmaf(k, v.w, acc[j].w);
    }
  }

  // epilogue: res = 4*(xp - gauss); xp = xs[r+11][c+11]
  float* rb = res + (size_t)z * HW + (size_t)(tby * 64) * WID + tbx * 64;
#pragma unroll
  for (int j = 0; j < 4; ++j) {
    const float* xr = &xs[(rt + j + PAD) * XS + ct];
    float4 A = *(const float4*)(xr + 8);
    float4 B = *(const float4*)(xr + 12);
    float4 o;
    o.x = 4.0f * (A.w - acc[j].x);
    o.y = 4.0f * (B.x - acc[j].y);
    o.z = 4.0f * (B.y - acc[j].z);
    o.w = 4.0f * (B.z - acc[j].w);
    *(float4*)&rb[(size_t)(rt + j) * WID + ct] = o;
  }
}

// ---------- per-plane histogram of trunc(res*256) ----------
__global__ __launch_bounds__(256) void hist_kernel(const float* __restrict__ res,
                                                   int* __restrict__ ghist) {
  __shared__ int h[16384];
  const int p = blockIdx.x, s = blockIdx.y, tid = threadIdx.x;
  for (int i = tid; i < 16384; i += 256) h[i] = 0;
  __syncthreads();
  const float4* rv = (const float4*)(res + (size_t)p * HW + (size_t)s * (HW / 16));
#define HADD(c) { int b = (int)((c) * 256.0f) + 8192; b = min(max(b, 0), 16383); atomicAdd(&h[b], 1); }
  for (int i = tid; i < HW / 16 / 4; i += 256) {
    float4 v = rv[i];
    HADD(v.x); HADD(v.y); HADD(v.z); HADD(v.w);
  }
#undef HADD
  __syncthreads();
  int* gh = ghist + p * 16384;
  const int st = (s * 1024) & 16383;
  for (int k = tid; k < 16384; k += 256) {
    int i = (k + st) & 16383;
    int c = h[i];
    if (c) atomicAdd(&gh[i], c);
  }
}

// ---------- percentile scan (np.percentile linear interp) ----------
__global__ __launch_bounds__(256) void pct_kernel(const int* __restrict__ ghist,
                                                  float* __restrict__ lo_out,
                                                  float* __restrict__ inv_out) {
  __shared__ int csum[256];
  const int p = blockIdx.x, tid = threadIdx.x;
  const int* gh = ghist + p * 16384;
  int s = 0;
  for (int j = 0; j < 64; ++j) s += gh[tid * 64 + j];
  csum[tid] = s;
  __syncthreads();
  if (tid == 0) {
    auto find_rank = [&](int rank) -> float {
      int cum = 0, ch = 0;
      for (; ch < 255; ++ch) { if (cum + csum[ch] >= rank) break; cum += csum[ch]; }
      int b = ch * 64;
      for (int j = 0; j < 64; ++j) { if (cum + gh[b] >= rank) break; cum += gh[b]; ++b; }
      if (b > 16383) b = 16383;
      return (float)(b - 8192) * 0.00390625f;
    };
    double pl = 0.03 * (double)(HW - 1);
    int kl = (int)pl;
    double fl = pl - (double)kl;
    float v0 = find_rank(kl + 1), v1 = find_rank(kl + 2);
    double lov = (double)v0 + fl * ((double)v1 - (double)v0);
    double ph = 0.97 * (double)(HW - 1);
    int kh = (int)ph;
    double fh = ph - (double)kh;
    float w0 = find_rank(kh + 1), w1 = find_rank(kh + 2);
    double hiv = (double)w0 + fh * ((double)w1 - (double)w0);
    lo_out[p] = (float)lov;
    inv_out[p] = (float)(1.0 / (hiv - lov));
  }
}

// ---------- final normalize in place (res lives in d_out) ----------
__global__ __launch_bounds__(256) void final_kernel(float* __restrict__ res,
                                                    const float* __restrict__ mask,
                                                    const float* __restrict__ lo,
                                                    const float* __restrict__ inv) {
  const int i = blockIdx.x * 256 + threadIdx.x;
  const int e = i << 2;
  const int z = e >> 18;
  const int n = z / NCH;
  const int hw = e & (HW - 1);
  float4 r = ((const float4*)res)[i];
  float4 m = *(const float4*)(mask + (size_t)n * HW + hw);
  const float l = lo[z];
  const float iv = inv[z];
  float4 o;
  o.x = (r.x - l) * iv * m.x;
  o.y = (r.y - l) * iv * m.y;
  o.z = (r.z - l) * iv * m.z;
  o.w = (r.w - l) * iv * m.w;
  ((float4*)res)[i] = o;
}

extern "C" void kernel_launch(void* const* d_in, const int* in_sizes, int n_in,
                              void* d_out, int out_size, void* d_ws, size_t ws_size,
                              hipStream_t stream) {
  (void)in_sizes; (void)n_in; (void)out_size; (void)ws_size;
  const float* x = (const float*)d_in[0];
  const float* mask = (const float*)d_in[1];
  const float* kern = (const float*)d_in[2];
  float* out = (float*)d_out;  // doubles as res scratch

  int* hist = (int*)d_ws;                 // 48*16384
  int* ghist1 = hist + PLANES * 16384;    // 48*8192
  float* med = (float*)(ghist1 + PLANES * 8192);
  float* lo = med + PLANES;
  float* inv = lo + PLANES;
  float* k1g = inv + PLANES;              // 23 floats

  hipMemsetAsync(hist, 0, (size_t)PLANES * (16384 + 8192) * sizeof(int), stream);
  kprep_kernel<<<1, 64, 0, stream>>>(kern, k1g);
  hist1_kernel<<<dim3(PLANES, 16), 256, 0, stream>>>(x, ghist1);
  scan_med_kernel<<<PLANES, 256, 0, stream>>>(ghist1, med);
  conv_kernel<<<dim3(8, 8, PLANES), 256, 0, stream>>>(x, mask, k1g, med, out);
  hist_kernel<<<dim3(PLANES, 16), 256, 0, stream>>>(out, hist);
  pct_kernel<<<PLANES, 256, 0, stream>>>(hist, lo, inv);
  final_kernel<<<(HW * PLANES / 4 + 255) / 256, 256, 0, stream>>>(out, mask, lo, inv);
}

// Round 4
// 214.217 us; speedup vs baseline: 2.1916x; 1.2309x over previous
//
#include <hip/hip_runtime.h>

#define HW 262144
#define WID 512
#define PLANES 48
#define NCH 3
#define PAD 11
#define FW 23
#define XS 92   // xs row stride (floats): 92%32=28 -> phase-disjoint bank sets
#define HS 64   // hs row stride (floats): phase = single row = conflict-free

// ---------- median: single-pass 8192-bin histogram over [-8,8) ----------
__global__ __launch_bounds__(256) void hist1_kernel(const float* __restrict__ x,
                                                    int* __restrict__ ghist1) {
  __shared__ int h[8192];
  const int p = blockIdx.x, s = blockIdx.y, tid = threadIdx.x;
  for (int i = tid; i < 8192; i += 256) h[i] = 0;
  __syncthreads();
  const float4* xv = (const float4*)(x + (size_t)p * HW + (size_t)s * (HW / 16));
#define H1(c) { int b = (int)(((c) + 8.0f) * 512.0f); b = min(max(b, 0), 8191); atomicAdd(&h[b], 1); }
  for (int i = tid; i < HW / 16 / 4; i += 256) {
    float4 v = xv[i];
    H1(v.x); H1(v.y); H1(v.z); H1(v.w);
  }
#undef H1
  __syncthreads();
  int* gh = ghist1 + p * 8192;
  const int st = (s * 512) & 8191;
  for (int k = tid; k < 8192; k += 256) {
    int i = (k + st) & 8191;
    int c = h[i];
    if (c) atomicAdd(&gh[i], c);
  }
}

// ---------- parallel median select (+ k1 prep piggybacked) ----------
__global__ __launch_bounds__(256) void scan_med_kernel(const int* __restrict__ ghist1,
                                                       float* __restrict__ med,
                                                       const float* __restrict__ kern,
                                                       float* __restrict__ k1g) {
  __shared__ int incl[256];
  __shared__ int s_chunk, s_base;
  const int p = blockIdx.x, t = threadIdx.x;
  if (p == 0 && t < FW) k1g[t] = kern[t * FW + PAD] / sqrtf(kern[PAD * FW + PAD]);
  const int* gh = ghist1 + p * 8192;
  int mysum = 0;
#pragma unroll
  for (int j = 0; j < 32; ++j) mysum += gh[t * 32 + j];
  incl[t] = mysum;
  __syncthreads();
  for (int off = 1; off < 256; off <<= 1) {
    int v = (t >= off) ? incl[t - off] : 0;
    __syncthreads();
    incl[t] += v;
    __syncthreads();
  }
  const int rank = 131072;  // 1-based rank of sorted idx (HW-1)/2
  {
    int excl = incl[t] - mysum;
    if (excl < rank && rank <= incl[t]) { s_chunk = t; s_base = rank - excl; }
  }
  __syncthreads();
  if (t < 64) {
    const int c = s_chunk, base = s_base;
    int cnt = (t < 32) ? gh[c * 32 + t] : 0;
    int pfx = cnt;
#pragma unroll
    for (int off = 1; off < 32; off <<= 1) {
      int u = __shfl_up(pfx, off, 64);
      if (t >= off) pfx += u;
    }
    unsigned long long m = __ballot(t < 32 && pfx >= base);
    int bin = c * 32 + (__ffsll((long long)m) - 1);
    if (t == 0) med[p] = -8.0f + ((float)bin + 0.5f) * 0.001953125f + 0.2f;
  }
}

// ---------- separable 23x23 conv, register-tiled ----------
__global__ __launch_bounds__(256) void conv_kernel(const float* __restrict__ x,
                                                   const float* __restrict__ mask,
                                                   const float* __restrict__ k1g,
                                                   const float* __restrict__ med,
                                                   float* __restrict__ res) {
  __shared__ float xs[86 * XS];  // 31648 B
  __shared__ float hs[86 * HS];  // 22016 B
  const int z = blockIdx.z;
  const int n = z / NCH;
  const int tbx = blockIdx.x, tby = blockIdx.y;
  const int tid = threadIdx.x;

  float k1[FW];
#pragma unroll
  for (int t = 0; t < FW; ++t) k1[t] = k1g[t];

  const float m_med = med[z];
  const int gr0 = tby * 64 - PAD;
  const int gc0 = tbx * 64 - PAD;
  const float* xb = x + (size_t)z * HW;
  const float* mb = mask + (size_t)n * HW;
  for (int i = tid; i < 86 * 86; i += 256) {
    int r = i / 86, c = i - r * 86;
    int gr = min(max(gr0 + r, 0), WID - 1);
    int gc = min(max(gc0 + c, 0), WID - 1);
    int g = gr * WID + gc;
    float xv = xb[g], mv = mb[g];
    xs[r * XS + c] = fmaf(mv, xv - m_med, m_med);
  }
  __syncthreads();

  // horizontal: 8 outputs per task; 86 rows x 8 groups
  for (int g = tid; g < 86 * 8; g += 256) {
    int r = g >> 3, c0 = (g & 7) << 3;
    const float* row = &xs[r * XS + c0];
    float w[32];
#pragma unroll
    for (int q = 0; q < 8; ++q) *(float4*)&w[q * 4] = *(const float4*)(row + q * 4);
    float a[8];
#pragma unroll
    for (int j = 0; j < 8; ++j) a[j] = 0.f;
#pragma unroll
    for (int t = 0; t < FW; ++t) {
      float k = k1[t];
#pragma unroll
      for (int j = 0; j < 8; ++j) a[j] = fmaf(k, w[t + j], a[j]);
    }
    *(float4*)&hs[r * HS + c0] = make_float4(a[0], a[1], a[2], a[3]);
    *(float4*)&hs[r * HS + c0 + 4] = make_float4(a[4], a[5], a[6], a[7]);
  }
  __syncthreads();

  // vertical: 4x4 micro-tile per thread
  const int ct = (tid & 15) << 2;
  const int rt = (tid >> 4) << 2;
  float4 acc[4];
#pragma unroll
  for (int j = 0; j < 4; ++j) acc[j] = make_float4(0.f, 0.f, 0.f, 0.f);
#pragma unroll
  for (int tp = 0; tp < 26; ++tp) {
    float4 v = *(const float4*)&hs[(rt + tp) * HS + ct];
    const int jlo = (tp - 22 > 0) ? (tp - 22) : 0;
    const int jhi = (tp < 3) ? tp : 3;
#pragma unroll
    for (int j = jlo; j <= jhi; ++j) {
      float k = k1[tp - j];
      acc[j].x = fmaf(k, v.x, acc[j].x);
      acc[j].y = fmaf(k, v.y, acc[j].y);
      acc[j].z = fmaf(k, v.z, acc[j].z);
      acc[j].w = fmaf(k, v.w, acc[j].w);
    }
  }

  float* rb = res + (size_t)z * HW + (size_t)(tby * 64) * WID + tbx * 64;
#pragma unroll
  for (int j = 0; j < 4; ++j) {
    const float* xr = &xs[(rt + j + PAD) * XS + ct];
    float4 A = *(const float4*)(xr + 8);
    float4 B = *(const float4*)(xr + 12);
    float4 o;
    o.x = 4.0f * (A.w - acc[j].x);
    o.y = 4.0f * (B.x - acc[j].y);
    o.z = 4.0f * (B.y - acc[j].z);
    o.w = 4.0f * (B.z - acc[j].w);
    *(float4*)&rb[(size_t)(rt + j) * WID + ct] = o;
  }
}

// ---------- per-plane histogram of trunc(res*256), 8192 bins over [-16,16) ----------
__global__ __launch_bounds__(256) void hist_kernel(const float* __restrict__ res,
                                                   int* __restrict__ ghist) {
  __shared__ int h[8192];
  const int p = blockIdx.x, s = blockIdx.y, tid = threadIdx.x;
  for (int i = tid; i < 8192; i += 256) h[i] = 0;
  __syncthreads();
  const float4* rv = (const float4*)(res + (size_t)p * HW + (size_t)s * (HW / 16));
#define HADD(c) { int b = (int)((c) * 256.0f) + 4096; b = min(max(b, 0), 8191); atomicAdd(&h[b], 1); }
  for (int i = tid; i < HW / 16 / 4; i += 256) {
    float4 v = rv[i];
    HADD(v.x); HADD(v.y); HADD(v.z); HADD(v.w);
  }
#undef HADD
  __syncthreads();
  int* gh = ghist + p * 8192;
  const int st = (s * 512) & 8191;
  for (int k = tid; k < 8192; k += 256) {
    int i = (k + st) & 8191;
    int c = h[i];
    if (c) atomicAdd(&gh[i], c);
  }
}

// ---------- parallel percentile select ----------
__global__ __launch_bounds__(256) void pct_kernel(const int* __restrict__ ghist,
                                                  float* __restrict__ lo_out,
                                                  float* __restrict__ inv_out) {
  __shared__ int incl[256];
  __shared__ int s_chunk, s_base;
  __shared__ float s_v[4];
  const int p = blockIdx.x, t = threadIdx.x;
  const int* gh = ghist + p * 8192;
  int mysum = 0;
#pragma unroll
  for (int j = 0; j < 32; ++j) mysum += gh[t * 32 + j];
  incl[t] = mysum;
  __syncthreads();
  for (int off = 1; off < 256; off <<= 1) {
    int v = (t >= off) ? incl[t - off] : 0;
    __syncthreads();
    incl[t] += v;
    __syncthreads();
  }
  // 1-based ranks: lo -> 7865,7866 (frac .29); hi -> 254279,254280 (frac .71)
  const int ranks[4] = {7865, 7866, 254279, 254280};
#pragma unroll
  for (int r = 0; r < 4; ++r) {
    const int rank = ranks[r];
    int excl = incl[t] - mysum;
    if (excl < rank && rank <= incl[t]) { s_chunk = t; s_base = rank - excl; }
    __syncthreads();
    if (t < 64) {
      const int c = s_chunk, base = s_base;
      int cnt = (t < 32) ? gh[c * 32 + t] : 0;
      int pfx = cnt;
#pragma unroll
      for (int off = 1; off < 32; off <<= 1) {
        int u = __shfl_up(pfx, off, 64);
        if (t >= off) pfx += u;
      }
      unsigned long long m = __ballot(t < 32 && pfx >= base);
      int bin = c * 32 + (__ffsll((long long)m) - 1);
      if (t == 0) s_v[r] = (float)(bin - 4096) * 0.00390625f;
    }
    __syncthreads();
  }
  if (t == 0) {
    const double fl = 0.29, fh = 0.71;
    double lov = (double)s_v[0] + fl * ((double)s_v[1] - (double)s_v[0]);
    double hiv = (double)s_v[2] + fh * ((double)s_v[3] - (double)s_v[2]);
    lo_out[p] = (float)lov;
    inv_out[p] = (float)(1.0 / (hiv - lov));
  }
}

// ---------- final normalize in place (res lives in d_out) ----------
__global__ __launch_bounds__(256) void final_kernel(float* __restrict__ res,
                                                    const float* __restrict__ mask,
                                                    const float* __restrict__ lo,
                                                    const float* __restrict__ inv) {
  const int i = blockIdx.x * 256 + threadIdx.x;
  const int e = i << 2;
  const int z = e >> 18;
  const int n = z / NCH;
  const int hw = e & (HW - 1);
  float4 r = ((const float4*)res)[i];
  float4 m = *(const float4*)(mask + (size_t)n * HW + hw);
  const float l = lo[z];
  const float iv = inv[z];
  float4 o;
  o.x = (r.x - l) * iv * m.x;
  o.y = (r.y - l) * iv * m.y;
  o.z = (r.z - l) * iv * m.z;
  o.w = (r.w - l) * iv * m.w;
  ((float4*)res)[i] = o;
}

extern "C" void kernel_launch(void* const* d_in, const int* in_sizes, int n_in,
                              void* d_out, int out_size, void* d_ws, size_t ws_size,
                              hipStream_t stream) {
  (void)in_sizes; (void)n_in; (void)out_size; (void)ws_size;
  const float* x = (const float*)d_in[0];
  const float* mask = (const float*)d_in[1];
  const float* kern = (const float*)d_in[2];
  float* out = (float*)d_out;  // doubles as res scratch

  int* hist = (int*)d_ws;                 // 48*8192
  int* ghist1 = hist + PLANES * 8192;     // 48*8192
  float* med = (float*)(ghist1 + PLANES * 8192);
  float* lo = med + PLANES;
  float* inv = lo + PLANES;
  float* k1g = inv + PLANES;              // 23 floats

  hipMemsetAsync(hist, 0, (size_t)PLANES * (8192 + 8192) * sizeof(int), stream);
  hist1_kernel<<<dim3(PLANES, 16), 256, 0, stream>>>(x, ghist1);
  scan_med_kernel<<<PLANES, 256, 0, stream>>>(ghist1, med, kern, k1g);
  conv_kernel<<<dim3(8, 8, PLANES), 256, 0, stream>>>(x, mask, k1g, med, out);
  hist_kernel<<<dim3(PLANES, 16), 256, 0, stream>>>(out, hist);
  pct_kernel<<<PLANES, 256, 0, stream>>>(hist, lo, inv);
  final_kernel<<<(HW * PLANES / 4 + 255) / 256, 256, 0, stream>>>(out, mask, lo, inv);
}